// Round 13
// baseline (1726.602 us; speedup 1.0000x reference)
//
#include <hip/hip_runtime.h>

#define TLEN 8249
#define TPAD 8320          // 130*64
#define NTILES 130
#define NB 4
#define NAUX 54
#define NQ 256
#define HID 192
#define NSKIP 256
#define KW 6
#define UPF 110
#define TAUX 75
#define PADR 180           // 5*36 max left reach of dilated conv
#define HROWS (PADR + TPAD)

typedef __attribute__((ext_vector_type(8))) short bf16x8v;
typedef __attribute__((ext_vector_type(4))) float f32x4;

__device__ __forceinline__ unsigned short f2bf(float f) {
  unsigned int u = __float_as_uint(f);
  u += 0x7FFFu + ((u >> 16) & 1u);   // RNE
  return (unsigned short)(u >> 16);
}

__device__ __forceinline__ f32x4 mfma16(bf16x8v a, bf16x8v b, f32x4 c) {
  return __builtin_amdgcn_mfma_f32_16x16x32_bf16(a, b, c, 0, 0, 0);
}

// ---------------- weight prepack (MFMA fragment order) + C vector ----------
__global__ void prepack_kernel(
    const float* causal_w, const float* dilh_w, const float* skip_w,
    const float* out1_w, const float* out2_w,
    const float* inx_w, const float* inx_b, const float* up_b,
    unsigned short* pk_causal, unsigned short* pk_dilh, unsigned short* pk_skip,
    unsigned short* pk_out1, unsigned short* pk_out2, float* Cbuf)
{
  int i = blockIdx.x * blockDim.x + threadIdx.x;
  if (i < 9*6*6*24*64*8) {            // dilh: [l][tap][kc6][nf24][lane][8]
    int t = i;
    int j = t & 7; t >>= 3;
    int lane = t & 63; t >>= 6;
    int nf = t % 24; t /= 24;
    int kc = t % 6; t /= 6;
    int tap = t % 6; t /= 6;
    int l = t;
    int oc = nf*16 + (lane & 15);
    int ic = kc*32 + ((lane >> 4) << 3) + j;
    pk_dilh[i] = f2bf(dilh_w[((l*384 + oc)*HID + ic)*KW + tap]);
  }
  if (i < 6*8*12*64*8) {              // causal: [tap][kc8][nf12][lane][8]
    int t = i;
    int j = t & 7; t >>= 3;
    int lane = t & 63; t >>= 6;
    int nf = t % 12; t /= 12;
    int kc = t % 8; t /= 8;
    int tap = t;
    int oc = nf*16 + (lane & 15);
    int ic = kc*32 + ((lane >> 4) << 3) + j;
    pk_causal[i] = f2bf(causal_w[(oc*NQ + ic)*KW + tap]);
  }
  if (i < 9*6*16*64*8) {              // skip: [l][kc6][nf16][lane][8]
    int t = i;
    int j = t & 7; t >>= 3;
    int lane = t & 63; t >>= 6;
    int nf = t % 16; t /= 16;
    int kc = t % 6; t /= 6;
    int l = t;
    int sc = nf*16 + (lane & 15);
    int ic = kc*32 + ((lane >> 4) << 3) + j;
    pk_skip[i] = f2bf(skip_w[(l*NSKIP + sc)*HID + ic]);
  }
  if (i < 8*16*64*8) {                // out1/out2: [kc8][nf16][lane][8]
    int t = i;
    int j = t & 7; t >>= 3;
    int lane = t & 63; t >>= 6;
    int nf = t % 16; t /= 16;
    int kc = t;
    int oq = nf*16 + (lane & 15);
    int sc = kc*32 + ((lane >> 4) << 3) + j;
    pk_out1[i] = f2bf(out1_w[oq*NSKIP + sc]);
    pk_out2[i] = f2bf(out2_w[oq*NQ + sc]);
  }
  if (i < 9*384) {                    // C[l][oc] = up_b*rowsum(inx_w)+inx_b
    int l = i / 384, oc = i % 384;
    const float* wr = inx_w + (l*384 + oc)*486;
    float s = 0.f;
    for (int c = 0; c < 486; c++) s += wr[c];
    Cbuf[i] = up_b[0]*s + inx_b[i];
  }
}

// ---------------- zero the 180-row causal pads of all 9 h slabs ------------
__global__ void zpad_kernel(unsigned short* h_all) {
  int i = blockIdx.x*blockDim.x + threadIdx.x;
  if (i < 9*NB*PADR*HID) {
    int slab = i / (NB*PADR*HID), r = i % (NB*PADR*HID);
    int b = r / (PADR*HID), rr = r % (PADR*HID);
    h_all[((size_t)slab*NB + b)*HROWS*HID + rr] = 0;
  }
}

// ---------------- tiny aux chain (all fp32) --------------------------------
__global__ void aux1_kernel(const float* aux, const float* w, const float* bias, float* a1) {
  int q = blockIdx.x, b = blockIdx.y, co = threadIdx.x;
  if (co >= NAUX) return;
  float acc = bias[co];
  for (int ci = 0; ci < NAUX; ci++)
    acc += w[co*NAUX + ci] * aux[(b*NAUX + ci)*TAUX + q];
  a1[(b*NAUX + co)*TAUX + q] = acc;
}

__global__ void aux2_kernel(const float* a1, const float* w, const float* bias, float* a2) {
  __shared__ float s[3][NAUX];
  int q = blockIdx.x, b = blockIdx.y, tid = threadIdx.x;
  for (int i = tid; i < 3*NAUX; i += blockDim.x) {
    int k = i / NAUX, c = i % NAUX;
    int qq = q - 1 + k;
    s[k][c] = (qq >= 0 && qq < TAUX) ? a1[(b*NAUX + c)*TAUX + qq] : 0.f;
  }
  __syncthreads();
  int co = tid;
  if (co >= 162) return;
  float acc = bias[co];
  for (int c = 0; c < NAUX; c++)
    #pragma unroll
    for (int k = 0; k < 3; k++)
      acc += w[(co*NAUX + c)*3 + k] * s[k][c];
  a2[(b*162 + co)*TAUX + q] = acc;
}

__global__ void aux3_kernel(const float* a2, const float* w, const float* bias, float* a3) {
  __shared__ float s[3][162];
  int q = blockIdx.x, b = blockIdx.y, tid = threadIdx.x;
  for (int i = tid; i < 3*162; i += blockDim.x) {
    int k = i / 162, c = i % 162;
    int qq = q + 3*(k - 1);
    s[k][c] = (qq >= 0 && qq < TAUX) ? a2[(b*162 + c)*TAUX + qq] : 0.f;
  }
  __syncthreads();
  int co = tid;
  if (co >= 486) return;
  float acc = bias[co];
  for (int c = 0; c < 162; c++)
    #pragma unroll
    for (int k = 0; k < 3; k++)
      acc += w[(co*162 + c)*3 + k] * s[k][c];
  a3[(b*486 + co)*TAUX + q] = acc;
}

// ---------------- G[l][b][q][oc] = sum_c inx_w[l][oc][c] * a3[b][c][q] -----
__global__ void g_kernel(const float* a3, const float* inx_w, float* G) {
  __shared__ float s[486][15];
  int q0 = blockIdx.x * 15, b = blockIdx.y, l = blockIdx.z;
  int tid = threadIdx.x;
  for (int i = tid; i < 486*15; i += 384) {
    int c = i / 15, qq = i % 15;
    s[c][qq] = a3[(b*486 + c)*TAUX + q0 + qq];
  }
  __syncthreads();
  int oc = tid;
  float acc[15];
  #pragma unroll
  for (int qq = 0; qq < 15; qq++) acc[qq] = 0.f;
  const float* wrow = inx_w + (l*384 + oc)*486;
  for (int c = 0; c < 486; c++) {
    float w = wrow[c];
    #pragma unroll
    for (int qq = 0; qq < 15; qq++) acc[qq] += w * s[c][qq];
  }
  for (int qq = 0; qq < 15; qq++)
    G[((size_t)(l*NB + b)*TAUX + q0 + qq)*384 + oc] = acc[qq];
}

// ---------------- causal conv (256ch K=6) + softsign -> h0 (bf16) ----------
__global__ __launch_bounds__(256, 2)
void causal_kernel(const float* audio, const unsigned short* pk, const float* cb,
                   unsigned short* hbf)
{
  __shared__ __align__(16) unsigned short sA[72*264];   // [t_win][ic pad264]
  int b = blockIdx.y, t0 = blockIdx.x*64, tid = threadIdx.x;
  int wv = tid >> 6, lane = tid & 63, lanelo = lane & 15;

  for (int i = tid; i < 72*256; i += 256) {   // stage audio tile, bf16
    int ic = i / 72, tt = i % 72;
    int t = t0 - 5 + tt;
    float v = (t >= 0 && t < TLEN) ? audio[(size_t)(b*NQ + ic)*TLEN + t] : 0.f;
    sA[tt*264 + ic] = f2bf(v);
  }
  __syncthreads();

  f32x4 acc[4][3];
  f32x4 z4 = {0.f, 0.f, 0.f, 0.f};
  #pragma unroll
  for (int m = 0; m < 4; m++)
    #pragma unroll
    for (int i = 0; i < 3; i++) acc[m][i] = z4;

  for (int tap = 0; tap < 6; tap++) {
    for (int kc = 0; kc < 8; kc++) {
      bf16x8v A[4];
      int ko = kc*32 + ((lane >> 4) << 3);
      #pragma unroll
      for (int m = 0; m < 4; m++)
        A[m] = *(const bf16x8v*)&sA[(m*16 + lanelo + tap)*264 + ko];
      #pragma unroll
      for (int i = 0; i < 3; i++) {
        int nf = wv*3 + i;
        bf16x8v Bf = *(const bf16x8v*)&pk[(size_t)((((tap*8) + kc)*12 + nf)*64 + lane)*8];
        #pragma unroll
        for (int m = 0; m < 4; m++) acc[m][i] = mfma16(A[m], Bf, acc[m][i]);
      }
    }
  }

  #pragma unroll
  for (int m = 0; m < 4; m++)
    #pragma unroll
    for (int i = 0; i < 3; i++) {
      int oc = (wv*3 + i)*16 + lanelo;
      float bias = cb[oc];
      #pragma unroll
      for (int r = 0; r < 4; r++) {
        int tl = m*16 + ((lane >> 4) << 2) + r;
        int t = t0 + tl;
        float v = acc[m][i][r] + bias;
        float h0 = v / (1.f + fabsf(v));
        hbf[(size_t)(b*HROWS + t + PADR)*HID + oc] = f2bf(h0);
      }
    }
}

// ---------------- union-window layer body (templated on dil) ---------------
template<int DIL, int MAXW>
__device__ __forceinline__
void layer_u_body(const unsigned short* __restrict__ hin,
                  unsigned short* __restrict__ hout,
                  const unsigned short* __restrict__ pk_dilh_l,
                  const float* __restrict__ dilh_b_l,
                  const float* __restrict__ Gl, const float* __restrict__ Cl,
                  const float* __restrict__ up_w,
                  unsigned short* flat)
{
  int b = blockIdx.y, t0 = blockIdx.x*64, tid = threadIdx.x;
  int wv = tid >> 6, lane = tid & 63, lanelo = lane & 15, lanehi = lane >> 4;

  const size_t hbase = (size_t)b * HROWS * HID;
  int rowbase0 = t0 - 5*DIL + PADR;            // >= 0 always
  const int W = 64 + 5*DIL;

  for (int c = tid; c < W*24; c += 256) {
    int row = c/24, cbk = c%24;
    uint4 v = *(const uint4*)&hin[hbase + (size_t)(rowbase0+row)*HID + cbk*8];
    *(uint4*)&flat[row*192 + ((cbk ^ (row&7))<<3)] = v;
  }
  __syncthreads();

  f32x4 accz[4][3], acct[4][3];
  f32x4 z4 = {0.f, 0.f, 0.f, 0.f};
  #pragma unroll
  for (int m = 0; m < 4; m++)
    #pragma unroll
    for (int i = 0; i < 3; i++) { accz[m][i] = z4; acct[m][i] = z4; }

  for (int tap = 0; tap < 6; tap++) {
    #pragma unroll
    for (int kc = 0; kc < 6; kc++) {
      bf16x8v A[4];
      #pragma unroll
      for (int m = 0; m < 4; m++) {
        int r = m*16 + lanelo + tap*DIL;
        int cbk = kc*4 + lanehi;
        A[m] = *(const bf16x8v*)&flat[r*192 + ((cbk ^ (r&7))<<3)];
      }
      #pragma unroll
      for (int i = 0; i < 3; i++) {
        const unsigned short* bp =
            &pk_dilh_l[(size_t)(((tap*6 + kc)*24 + wv*3 + i)*64 + lane)*8];
        bf16x8v Bz = *(const bf16x8v*)bp;
        bf16x8v Bt = *(const bf16x8v*)(bp + 12*512);
        #pragma unroll
        for (int m = 0; m < 4; m++) {
          accz[m][i] = mfma16(A[m], Bz, accz[m][i]);
          acct[m][i] = mfma16(A[m], Bt, acct[m][i]);
        }
      }
    }
  }

  float izc[3], itc[3], bzc[3], btc[3];
  #pragma unroll
  for (int i = 0; i < 3; i++) {
    int ocz = (wv*3 + i)*16 + lanelo;
    izc[i] = Cl[ocz];       itc[i] = Cl[192 + ocz];
    bzc[i] = dilh_b_l[ocz]; btc[i] = dilh_b_l[192 + ocz];
  }
  #pragma unroll
  for (int m = 0; m < 4; m++) {
    #pragma unroll
    for (int r = 0; r < 4; r++) {
      int tl = m*16 + (lanehi << 2) + r;
      int t = t0 + tl;
      int hr = tl + 5*DIL;
      int tp1 = t + 1;
      int q = tp1 / UPF; if (q > TAUX - 1) q = TAUX - 1;
      int ui = tp1 - q*UPF; if (ui > UPF - 1) ui = UPF - 1;
      float u = up_w[ui];
      const float* Gb = Gl + (size_t)(b*TAUX + q)*384;
      #pragma unroll
      for (int i = 0; i < 3; i++) {
        int ocz = (wv*3 + i)*16 + lanelo;
        float iz = u*Gb[ocz]       + izc[i];
        float it = u*Gb[192 + ocz] + itc[i];
        float xz = (accz[m][i][r] + bzc[i]) * iz;
        float xt = (acct[m][i][r] + btc[i]) * it;
        float z  = 1.f / (1.f + __expf(-xz));
        float e2 = __expf(2.f*xt);
        float th = 1.f - 2.f/(e2 + 1.f);
        int cbh = ocz >> 3, jh = ocz & 7;
        unsigned short hob = flat[hr*192 + ((cbh ^ (hr&7))<<3) + jh];
        float hold = __uint_as_float(((unsigned int)hob) << 16);
        float hn = (1.f - z)*th + z*hold;
        hout[hbase + (size_t)(t + PADR)*HID + ocz] = f2bf(hn);
      }
    }
  }
}

// dil=1: 69 rows x 192 = 26.5KB -> 5 blocks/CU (20 waves)
__global__ __launch_bounds__(256, 5)
void layer_u1_kernel(const unsigned short* __restrict__ hin,
                     unsigned short* __restrict__ hout,
                     const unsigned short* __restrict__ pk_dilh_l,
                     const float* __restrict__ dilh_b_l,
                     const float* __restrict__ Gl, const float* __restrict__ Cl,
                     const float* __restrict__ up_w)
{
  __shared__ __align__(16) unsigned short flat[69*192];
  layer_u_body<1, 69>(hin, hout, pk_dilh_l, dilh_b_l, Gl, Cl, up_w, flat);
}

// dil=6: 94 rows x 192 = 36.1KB -> 4 blocks/CU (16 waves)
__global__ __launch_bounds__(256, 4)
void layer_u6_kernel(const unsigned short* __restrict__ hin,
                     unsigned short* __restrict__ hout,
                     const unsigned short* __restrict__ pk_dilh_l,
                     const float* __restrict__ dilh_b_l,
                     const float* __restrict__ Gl, const float* __restrict__ Cl,
                     const float* __restrict__ up_w)
{
  __shared__ __align__(16) unsigned short flat[94*192];
  layer_u_body<6, 94>(hin, hout, pk_dilh_l, dilh_b_l, Gl, Cl, up_w, flat);
}

// ---------------- layer (dil 36): M=64, per-tap dbuf strips, 3 blk/CU ------
__global__ __launch_bounds__(256, 3)
void layer_d_kernel(const unsigned short* __restrict__ hin,
                    unsigned short* __restrict__ hout,
                    const unsigned short* __restrict__ pk_dilh_l,
                    const float* __restrict__ dilh_b_l,
                    const float* __restrict__ Gl, const float* __restrict__ Cl,
                    const float* __restrict__ up_w)
{
  __shared__ __align__(16) unsigned short hs[2][64*192];   // 49152 B
  int b = blockIdx.y, t0 = blockIdx.x*64, tid = threadIdx.x;
  int wv = tid >> 6, lane = tid & 63, lanelo = lane & 15, lanehi = lane >> 4;

  const size_t hbase = (size_t)b * HROWS * HID;
  int rowbase0 = t0 - 180 + PADR;

  f32x4 accz[4][3], acct[4][3];
  f32x4 z4 = {0.f, 0.f, 0.f, 0.f};
  #pragma unroll
  for (int m = 0; m < 4; m++)
    #pragma unroll
    for (int i = 0; i < 3; i++) { accz[m][i] = z4; acct[m][i] = z4; }

  uint4 st[6];
  #pragma unroll
  for (int j = 0; j < 6; j++) {
    int c = tid + j*256, row = c/24, cbk = c%24;
    st[j] = *(const uint4*)&hin[hbase + (size_t)(rowbase0+row)*HID + cbk*8];
  }
  #pragma unroll
  for (int j = 0; j < 6; j++) {
    int c = tid + j*256, row = c/24, cbk = c%24;
    *(uint4*)&hs[0][row*192 + ((cbk ^ (row&7))<<3)] = st[j];
  }
  for (int tap = 0; tap < 6; tap++) {
    __syncthreads();
    if (tap < 5) {
      int rb = rowbase0 + (tap+1)*36;
      #pragma unroll
      for (int j = 0; j < 6; j++) {
        int c = tid + j*256, row = c/24, cbk = c%24;
        st[j] = *(const uint4*)&hin[hbase + (size_t)(rb+row)*HID + cbk*8];
      }
    }
    const unsigned short* bufc = hs[tap & 1];
    #pragma unroll
    for (int kc = 0; kc < 6; kc++) {
      bf16x8v A[4];
      #pragma unroll
      for (int m = 0; m < 4; m++) {
        int r = m*16 + lanelo;
        int cbk = kc*4 + lanehi;
        A[m] = *(const bf16x8v*)&bufc[r*192 + ((cbk ^ (r&7))<<3)];
      }
      #pragma unroll
      for (int i = 0; i < 3; i++) {
        const unsigned short* bp =
            &pk_dilh_l[(size_t)(((tap*6 + kc)*24 + wv*3 + i)*64 + lane)*8];
        bf16x8v Bz = *(const bf16x8v*)bp;
        bf16x8v Bt = *(const bf16x8v*)(bp + 12*512);
        #pragma unroll
        for (int m = 0; m < 4; m++) {
          accz[m][i] = mfma16(A[m], Bz, accz[m][i]);
          acct[m][i] = mfma16(A[m], Bt, acct[m][i]);
        }
      }
    }
    if (tap < 5) {
      unsigned short* bufn = hs[(tap+1) & 1];
      #pragma unroll
      for (int j = 0; j < 6; j++) {
        int c = tid + j*256, row = c/24, cbk = c%24;
        *(uint4*)&bufn[row*192 + ((cbk ^ (row&7))<<3)] = st[j];
      }
    }
  }

  float izc[3], itc[3], bzc[3], btc[3];
  #pragma unroll
  for (int i = 0; i < 3; i++) {
    int ocz = (wv*3 + i)*16 + lanelo;
    izc[i] = Cl[ocz];       itc[i] = Cl[192 + ocz];
    bzc[i] = dilh_b_l[ocz]; btc[i] = dilh_b_l[192 + ocz];
  }
  #pragma unroll
  for (int m = 0; m < 4; m++) {
    #pragma unroll
    for (int r = 0; r < 4; r++) {
      int tl = m*16 + (lanehi << 2) + r;
      int t = t0 + tl;
      int tp1 = t + 1;
      int q = tp1 / UPF; if (q > TAUX - 1) q = TAUX - 1;
      int ui = tp1 - q*UPF; if (ui > UPF - 1) ui = UPF - 1;
      float u = up_w[ui];
      const float* Gb = Gl + (size_t)(b*TAUX + q)*384;
      #pragma unroll
      for (int i = 0; i < 3; i++) {
        int ocz = (wv*3 + i)*16 + lanelo;
        float iz = u*Gb[ocz]       + izc[i];
        float it = u*Gb[192 + ocz] + itc[i];
        float xz = (accz[m][i][r] + bzc[i]) * iz;
        float xt = (acct[m][i][r] + btc[i]) * it;
        float z  = 1.f / (1.f + __expf(-xz));
        float e2 = __expf(2.f*xt);
        float th = 1.f - 2.f/(e2 + 1.f);
        int cbh = ocz >> 3, jh = ocz & 7;
        unsigned short hob = hs[1][tl*192 + ((cbh ^ (tl&7))<<3) + jh];
        float hold = __uint_as_float(((unsigned int)hob) << 16);
        float hn = (1.f - z)*th + z*hold;
        hout[hbase + (size_t)(t + PADR)*HID + ocz] = f2bf(hn);
      }
    }
  }
}

// ---------------- fused tail: skipsum -> relu -> out1 -> relu -> out2 ------
__global__ __launch_bounds__(256, 3)
void tail_kernel(const unsigned short* __restrict__ h_all,
                 const unsigned short* __restrict__ pk_skip,
                 const float* __restrict__ skip_b,
                 const unsigned short* __restrict__ pk1, const float* __restrict__ b1,
                 const unsigned short* __restrict__ pk2, const float* __restrict__ b2,
                 float* __restrict__ dout)
{
  __shared__ __align__(16) unsigned short ss[2][64*192];   // 49152 B
  int b = blockIdx.y, t0 = blockIdx.x*64, tid = threadIdx.x;
  int wv = tid >> 6, lane = tid & 63, lanelo = lane & 15, lanehi = lane >> 4;
  const size_t HS = (size_t)NB * HROWS * HID;
  f32x4 z4 = {0.f, 0.f, 0.f, 0.f};

  auto hsrc = [&](int l) {
    int slab = (l == 8) ? 0 : (l + 1);
    return h_all + (size_t)slab*HS + (size_t)b*HROWS*HID + (size_t)(t0 + PADR)*HID;
  };

  uint4 st[6];
  {
    const unsigned short* src = hsrc(0);
    #pragma unroll
    for (int j = 0; j < 6; j++) {
      int c = tid + j*256, row = c/24, cbk = c%24;
      st[j] = *(const uint4*)&src[(size_t)row*HID + cbk*8];
    }
    #pragma unroll
    for (int j = 0; j < 6; j++) {
      int c = tid + j*256, row = c/24, cbk = c%24;
      *(uint4*)&ss[0][row*192 + ((cbk ^ (row&7))<<3)] = st[j];
    }
  }

  f32x4 acc[4][4];
  #pragma unroll
  for (int m = 0; m < 4; m++)
    #pragma unroll
    for (int i = 0; i < 4; i++) acc[m][i] = z4;

  for (int l = 0; l < 9; l++) {
    __syncthreads();
    if (l < 8) {
      const unsigned short* src = hsrc(l + 1);
      #pragma unroll
      for (int j = 0; j < 6; j++) {
        int c = tid + j*256, row = c/24, cbk = c%24;
        st[j] = *(const uint4*)&src[(size_t)row*HID + cbk*8];
      }
    }
    const unsigned short* bufc = ss[l & 1];
    #pragma unroll
    for (int kc = 0; kc < 6; kc++) {
      bf16x8v A[4];
      #pragma unroll
      for (int m = 0; m < 4; m++) {
        int r = m*16 + lanelo;
        int cbk = kc*4 + lanehi;
        A[m] = *(const bf16x8v*)&bufc[r*192 + ((cbk ^ (r&7))<<3)];
      }
      #pragma unroll
      for (int i = 0; i < 4; i++) {
        bf16x8v Bf = *(const bf16x8v*)
            &pk_skip[(size_t)(((l*6 + kc)*16 + wv*4 + i)*64 + lane)*8];
        #pragma unroll
        for (int m = 0; m < 4; m++) acc[m][i] = mfma16(A[m], Bf, acc[m][i]);
      }
    }
    if (l < 8) {
      unsigned short* bufn = ss[(l+1) & 1];
      #pragma unroll
      for (int j = 0; j < 6; j++) {
        int c = tid + j*256, row = c/24, cbk = c%24;
        *(uint4*)&bufn[row*192 + ((cbk ^ (row&7))<<3)] = st[j];
      }
    }
  }
  __syncthreads();

  unsigned short* tile = &ss[0][0];
  #pragma unroll
  for (int i = 0; i < 4; i++) {
    int sc = (wv*4 + i)*16 + lanelo;
    float bias = 0.f;
    #pragma unroll
    for (int l = 0; l < 9; l++) bias += skip_b[l*NSKIP + sc];
    #pragma unroll
    for (int m = 0; m < 4; m++) {
      #pragma unroll
      for (int r = 0; r < 4; r++) {
        int tl = m*16 + (lanehi << 2) + r;
        tile[tl*264 + sc] = f2bf(fmaxf(acc[m][i][r] + bias, 0.f));
      }
    }
  }
  __syncthreads();

  // out1
  #pragma unroll
  for (int m = 0; m < 4; m++)
    #pragma unroll
    for (int i = 0; i < 4; i++) acc[m][i] = z4;
  for (int kc = 0; kc < 8; kc++) {
    bf16x8v A[4];
    int ko = kc*32 + (lanehi << 3);
    #pragma unroll
    for (int m = 0; m < 4; m++)
      A[m] = *(const bf16x8v*)&tile[(m*16 + lanelo)*264 + ko];
    #pragma unroll
    for (int i = 0; i < 4; i++) {
      bf16x8v Bf = *(const bf16x8v*)&pk1[(size_t)((kc*16 + wv*4 + i)*64 + lane)*8];
      #pragma unroll
      for (int m = 0; m < 4; m++) acc[m][i] = mfma16(A[m], Bf, acc[m][i]);
    }
  }
  __syncthreads();
  #pragma unroll
  for (int m = 0; m < 4; m++)
    #pragma unroll
    for (int i = 0; i < 4; i++) {
      int oq = (wv*4 + i)*16 + lanelo;
      float bias = b1[oq];
      #pragma unroll
      for (int r = 0; r < 4; r++) {
        int tl = m*16 + (lanehi << 2) + r;
        tile[tl*264 + oq] = f2bf(fmaxf(acc[m][i][r] + bias, 0.f));
      }
    }
  __syncthreads();

  // out2
  #pragma unroll
  for (int m = 0; m < 4; m++)
    #pragma unroll
    for (int i = 0; i < 4; i++) acc[m][i] = z4;
  for (int kc = 0; kc < 8; kc++) {
    bf16x8v A[4];
    int ko = kc*32 + (lanehi << 3);
    #pragma unroll
    for (int m = 0; m < 4; m++)
      A[m] = *(const bf16x8v*)&tile[(m*16 + lanelo)*264 + ko];
    #pragma unroll
    for (int i = 0; i < 4; i++) {
      bf16x8v Bf = *(const bf16x8v*)&pk2[(size_t)((kc*16 + wv*4 + i)*64 + lane)*8];
      #pragma unroll
      for (int m = 0; m < 4; m++) acc[m][i] = mfma16(A[m], Bf, acc[m][i]);
    }
  }
  float* so2 = (float*)&ss[0][0];
  #pragma unroll
  for (int p = 0; p < 2; p++) {
    __syncthreads();
    #pragma unroll
    for (int mm = 0; mm < 2; mm++) {
      int m = p*2 + mm;
      #pragma unroll
      for (int i = 0; i < 4; i++) {
        int oq = (wv*4 + i)*16 + lanelo;
        float bias = b2[oq];
        #pragma unroll
        for (int r = 0; r < 4; r++) {
          int lr = mm*16 + (lanehi << 2) + r;
          so2[lr*260 + oq] = acc[m][i][r] + bias;
        }
      }
    }
    __syncthreads();
    #pragma unroll
    for (int j = 0; j < 8; j++) {
      int c = tid + j*256, row = c >> 6, ch = c & 63;
      int t = t0 + p*32 + row;
      if (t < TLEN) {
        uint4 v = *(const uint4*)&so2[row*260 + ch*4];
        *(uint4*)&dout[(size_t)(b*TLEN + t)*NQ + ch*4] = v;
      }
    }
  }
}

// ---------------------------------------------------------------------------
extern "C" void kernel_launch(void* const* d_in, const int* in_sizes, int n_in,
                              void* d_out, int out_size, void* d_ws, size_t ws_size,
                              hipStream_t stream)
{
  const float* audio      = (const float*)d_in[0];
  const float* aux        = (const float*)d_in[1];
  const float* scale_in_w = (const float*)d_in[2];
  const float* scale_in_b = (const float*)d_in[3];
  const float* aux0_w     = (const float*)d_in[4];
  const float* aux0_b     = (const float*)d_in[5];
  const float* aux1_w     = (const float*)d_in[6];
  const float* aux1_b     = (const float*)d_in[7];
  const float* up_w       = (const float*)d_in[8];
  const float* up_b       = (const float*)d_in[9];
  const float* causal_w   = (const float*)d_in[10];
  const float* causal_b   = (const float*)d_in[11];
  const float* inx_w      = (const float*)d_in[12];
  const float* inx_b      = (const float*)d_in[13];
  const float* dilh_w     = (const float*)d_in[14];
  const float* dilh_b     = (const float*)d_in[15];
  const float* skip_w     = (const float*)d_in[16];
  const float* skip_b     = (const float*)d_in[17];
  const float* out1_w     = (const float*)d_in[18];
  const float* out1_b     = (const float*)d_in[19];
  const float* out2_w     = (const float*)d_in[20];
  const float* out2_b     = (const float*)d_in[21];

  char* ws = (char*)d_ws;
  size_t off = 0;
  auto alloc = [&](size_t bytes) -> void* {
    void* p = ws + off;
    off += (bytes + 255) & ~(size_t)255;
    return p;
  };
  unsigned short* pk_causal = (unsigned short*)alloc((size_t)6*8*12*64*8*2);
  unsigned short* pk_dilh   = (unsigned short*)alloc((size_t)9*6*6*24*64*8*2);
  unsigned short* pk_skip   = (unsigned short*)alloc((size_t)9*6*16*64*8*2);
  unsigned short* pk_out1   = (unsigned short*)alloc((size_t)8*16*64*8*2);
  unsigned short* pk_out2   = (unsigned short*)alloc((size_t)8*16*64*8*2);
  float* Cbuf    = (float*)alloc((size_t)9*384*4);
  float* a1      = (float*)alloc((size_t)NB*NAUX*TAUX*4);
  float* a2      = (float*)alloc((size_t)NB*162*TAUX*4);
  float* a3      = (float*)alloc((size_t)NB*486*TAUX*4);
  float* Gbuf    = (float*)alloc((size_t)9*NB*TAUX*384*4);
  const size_t HS = (size_t)NB*HROWS*HID;
  unsigned short* h_all = (unsigned short*)alloc((size_t)9*HS*2);  // slabs 0..8

  hipLaunchKernelGGL(prepack_kernel, dim3((9*6*6*24*64*8 + 255)/256), dim3(256), 0, stream,
                     causal_w, dilh_w, skip_w, out1_w, out2_w, inx_w, inx_b, up_b,
                     pk_causal, pk_dilh, pk_skip, pk_out1, pk_out2, Cbuf);
  hipLaunchKernelGGL(zpad_kernel, dim3((9*NB*PADR*HID + 255)/256), dim3(256), 0, stream,
                     h_all);
  hipLaunchKernelGGL(aux1_kernel, dim3(TAUX, NB), dim3(64), 0, stream,
                     aux, scale_in_w, scale_in_b, a1);
  hipLaunchKernelGGL(aux2_kernel, dim3(TAUX, NB), dim3(192), 0, stream,
                     a1, aux0_w, aux0_b, a2);
  hipLaunchKernelGGL(aux3_kernel, dim3(TAUX, NB), dim3(512), 0, stream,
                     a2, aux1_w, aux1_b, a3);
  hipLaunchKernelGGL(g_kernel, dim3(5, NB, 9), dim3(384), 0, stream,
                     a3, inx_w, Gbuf);
  hipLaunchKernelGGL(causal_kernel, dim3(NTILES, NB), dim3(256), 0, stream,
                     audio, pk_causal, causal_b, h_all /* slab 0 = h_0 */);

  const int dils[9] = {1, 6, 36, 1, 6, 36, 1, 6, 36};
  for (int l = 0; l < 9; l++) {
    const unsigned short* hin = h_all + (size_t)l*HS;
    unsigned short* hout      = (l == 8) ? h_all : h_all + (size_t)(l+1)*HS;
    const unsigned short* pkd = pk_dilh + (size_t)l*6*6*24*64*8;
    const float* dbl = dilh_b + (size_t)l*384;
    const float* Gl  = Gbuf + (size_t)l*NB*TAUX*384;
    const float* Cl  = Cbuf + (size_t)l*384;
    if (dils[l] == 1) {
      hipLaunchKernelGGL(layer_u1_kernel, dim3(NTILES, NB), dim3(256), 0, stream,
                         hin, hout, pkd, dbl, Gl, Cl, up_w);
    } else if (dils[l] == 6) {
      hipLaunchKernelGGL(layer_u6_kernel, dim3(NTILES, NB), dim3(256), 0, stream,
                         hin, hout, pkd, dbl, Gl, Cl, up_w);
    } else {
      hipLaunchKernelGGL(layer_d_kernel, dim3(NTILES, NB), dim3(256), 0, stream,
                         hin, hout, pkd, dbl, Gl, Cl, up_w);
    }
  }

  hipLaunchKernelGGL(tail_kernel, dim3(NTILES, NB), dim3(256), 0, stream,
                     h_all, pk_skip, skip_b, pk_out1, out1_b, pk_out2, out2_b,
                     (float*)d_out);
}

// Round 14
// 888.379 us; speedup vs baseline: 1.9435x; 1.9435x over previous
//
#include <hip/hip_runtime.h>

#define TLEN 8249
#define TPAD 8320          // 130*64
#define NTILES 130
#define NB 4
#define NAUX 54
#define NQ 256
#define HID 192
#define NSKIP 256
#define KW 6
#define UPF 110
#define TAUX 75
#define PADR 180           // 5*36 max left reach of dilated conv
#define HROWS (PADR + TPAD)

typedef __attribute__((ext_vector_type(8))) short bf16x8v;
typedef __attribute__((ext_vector_type(4))) float f32x4;

__device__ __forceinline__ unsigned short f2bf(float f) {
  unsigned int u = __float_as_uint(f);
  u += 0x7FFFu + ((u >> 16) & 1u);   // RNE
  return (unsigned short)(u >> 16);
}

__device__ __forceinline__ f32x4 mfma16(bf16x8v a, bf16x8v b, f32x4 c) {
  return __builtin_amdgcn_mfma_f32_16x16x32_bf16(a, b, c, 0, 0, 0);
}

// ---------------- weight prepack (MFMA fragment order) + C vector ----------
__global__ void prepack_kernel(
    const float* causal_w, const float* dilh_w, const float* skip_w,
    const float* out1_w, const float* out2_w,
    const float* inx_w, const float* inx_b, const float* up_b,
    unsigned short* pk_causal, unsigned short* pk_dilh, unsigned short* pk_skip,
    unsigned short* pk_out1, unsigned short* pk_out2, float* Cbuf)
{
  int i = blockIdx.x * blockDim.x + threadIdx.x;
  if (i < 9*6*6*24*64*8) {            // dilh: [l][tap][kc6][nf24][lane][8]
    int t = i;
    int j = t & 7; t >>= 3;
    int lane = t & 63; t >>= 6;
    int nf = t % 24; t /= 24;
    int kc = t % 6; t /= 6;
    int tap = t % 6; t /= 6;
    int l = t;
    int oc = nf*16 + (lane & 15);
    int ic = kc*32 + ((lane >> 4) << 3) + j;
    pk_dilh[i] = f2bf(dilh_w[((l*384 + oc)*HID + ic)*KW + tap]);
  }
  if (i < 6*8*12*64*8) {              // causal: [tap][kc8][nf12][lane][8]
    int t = i;
    int j = t & 7; t >>= 3;
    int lane = t & 63; t >>= 6;
    int nf = t % 12; t /= 12;
    int kc = t % 8; t /= 8;
    int tap = t;
    int oc = nf*16 + (lane & 15);
    int ic = kc*32 + ((lane >> 4) << 3) + j;
    pk_causal[i] = f2bf(causal_w[(oc*NQ + ic)*KW + tap]);
  }
  if (i < 9*6*16*64*8) {              // skip: [l][kc6][nf16][lane][8]
    int t = i;
    int j = t & 7; t >>= 3;
    int lane = t & 63; t >>= 6;
    int nf = t % 16; t /= 16;
    int kc = t % 6; t /= 6;
    int l = t;
    int sc = nf*16 + (lane & 15);
    int ic = kc*32 + ((lane >> 4) << 3) + j;
    pk_skip[i] = f2bf(skip_w[(l*NSKIP + sc)*HID + ic]);
  }
  if (i < 8*16*64*8) {                // out1/out2: [kc8][nf16][lane][8]
    int t = i;
    int j = t & 7; t >>= 3;
    int lane = t & 63; t >>= 6;
    int nf = t % 16; t /= 16;
    int kc = t;
    int oq = nf*16 + (lane & 15);
    int sc = kc*32 + ((lane >> 4) << 3) + j;
    pk_out1[i] = f2bf(out1_w[oq*NSKIP + sc]);
    pk_out2[i] = f2bf(out2_w[oq*NQ + sc]);
  }
  if (i < 9*384) {                    // C[l][oc] = up_b*rowsum(inx_w)+inx_b
    int l = i / 384, oc = i % 384;
    const float* wr = inx_w + (l*384 + oc)*486;
    float s = 0.f;
    for (int c = 0; c < 486; c++) s += wr[c];
    Cbuf[i] = up_b[0]*s + inx_b[i];
  }
}

// ---------------- zero the 180-row causal pads of all 9 h slabs ------------
__global__ void zpad_kernel(unsigned short* h_all) {
  int i = blockIdx.x*blockDim.x + threadIdx.x;
  if (i < 9*NB*PADR*HID) {
    int slab = i / (NB*PADR*HID), r = i % (NB*PADR*HID);
    int b = r / (PADR*HID), rr = r % (PADR*HID);
    h_all[((size_t)slab*NB + b)*HROWS*HID + rr] = 0;
  }
}

// ---------------- tiny aux chain (all fp32) --------------------------------
__global__ void aux1_kernel(const float* aux, const float* w, const float* bias, float* a1) {
  int q = blockIdx.x, b = blockIdx.y, co = threadIdx.x;
  if (co >= NAUX) return;
  float acc = bias[co];
  for (int ci = 0; ci < NAUX; ci++)
    acc += w[co*NAUX + ci] * aux[(b*NAUX + ci)*TAUX + q];
  a1[(b*NAUX + co)*TAUX + q] = acc;
}

__global__ void aux2_kernel(const float* a1, const float* w, const float* bias, float* a2) {
  __shared__ float s[3][NAUX];
  int q = blockIdx.x, b = blockIdx.y, tid = threadIdx.x;
  for (int i = tid; i < 3*NAUX; i += blockDim.x) {
    int k = i / NAUX, c = i % NAUX;
    int qq = q - 1 + k;
    s[k][c] = (qq >= 0 && qq < TAUX) ? a1[(b*NAUX + c)*TAUX + qq] : 0.f;
  }
  __syncthreads();
  int co = tid;
  if (co >= 162) return;
  float acc = bias[co];
  for (int c = 0; c < NAUX; c++)
    #pragma unroll
    for (int k = 0; k < 3; k++)
      acc += w[(co*NAUX + c)*3 + k] * s[k][c];
  a2[(b*162 + co)*TAUX + q] = acc;
}

__global__ void aux3_kernel(const float* a2, const float* w, const float* bias, float* a3) {
  __shared__ float s[3][162];
  int q = blockIdx.x, b = blockIdx.y, tid = threadIdx.x;
  for (int i = tid; i < 3*162; i += blockDim.x) {
    int k = i / 162, c = i % 162;
    int qq = q + 3*(k - 1);
    s[k][c] = (qq >= 0 && qq < TAUX) ? a2[(b*162 + c)*TAUX + qq] : 0.f;
  }
  __syncthreads();
  int co = tid;
  if (co >= 486) return;
  float acc = bias[co];
  for (int c = 0; c < 162; c++)
    #pragma unroll
    for (int k = 0; k < 3; k++)
      acc += w[(co*162 + c)*3 + k] * s[k][c];
  a3[(b*486 + co)*TAUX + q] = acc;
}

// ---------------- G[l][b][q][oc] = sum_c inx_w[l][oc][c] * a3[b][c][q] -----
__global__ void g_kernel(const float* a3, const float* inx_w, float* G) {
  __shared__ float s[486][15];
  int q0 = blockIdx.x * 15, b = blockIdx.y, l = blockIdx.z;
  int tid = threadIdx.x;
  for (int i = tid; i < 486*15; i += 384) {
    int c = i / 15, qq = i % 15;
    s[c][qq] = a3[(b*486 + c)*TAUX + q0 + qq];
  }
  __syncthreads();
  int oc = tid;
  float acc[15];
  #pragma unroll
  for (int qq = 0; qq < 15; qq++) acc[qq] = 0.f;
  const float* wrow = inx_w + (l*384 + oc)*486;
  for (int c = 0; c < 486; c++) {
    float w = wrow[c];
    #pragma unroll
    for (int qq = 0; qq < 15; qq++) acc[qq] += w * s[c][qq];
  }
  for (int qq = 0; qq < 15; qq++)
    G[((size_t)(l*NB + b)*TAUX + q0 + qq)*384 + oc] = acc[qq];
}

// ---------------- causal conv (256ch K=6) + softsign -> h0 (bf16) ----------
__global__ __launch_bounds__(256, 2)
void causal_kernel(const float* audio, const unsigned short* pk, const float* cb,
                   unsigned short* hbf)
{
  __shared__ __align__(16) unsigned short sA[72*264];   // [t_win][ic pad264]
  int b = blockIdx.y, t0 = blockIdx.x*64, tid = threadIdx.x;
  int wv = tid >> 6, lane = tid & 63, lanelo = lane & 15;

  for (int i = tid; i < 72*256; i += 256) {   // stage audio tile, bf16
    int ic = i / 72, tt = i % 72;
    int t = t0 - 5 + tt;
    float v = (t >= 0 && t < TLEN) ? audio[(size_t)(b*NQ + ic)*TLEN + t] : 0.f;
    sA[tt*264 + ic] = f2bf(v);
  }
  __syncthreads();

  f32x4 acc[4][3];
  f32x4 z4 = {0.f, 0.f, 0.f, 0.f};
  #pragma unroll
  for (int m = 0; m < 4; m++)
    #pragma unroll
    for (int i = 0; i < 3; i++) acc[m][i] = z4;

  for (int tap = 0; tap < 6; tap++) {
    for (int kc = 0; kc < 8; kc++) {
      bf16x8v A[4];
      int ko = kc*32 + ((lane >> 4) << 3);
      #pragma unroll
      for (int m = 0; m < 4; m++)
        A[m] = *(const bf16x8v*)&sA[(m*16 + lanelo + tap)*264 + ko];
      #pragma unroll
      for (int i = 0; i < 3; i++) {
        int nf = wv*3 + i;
        bf16x8v Bf = *(const bf16x8v*)&pk[(size_t)((((tap*8) + kc)*12 + nf)*64 + lane)*8];
        #pragma unroll
        for (int m = 0; m < 4; m++) acc[m][i] = mfma16(A[m], Bf, acc[m][i]);
      }
    }
  }

  #pragma unroll
  for (int m = 0; m < 4; m++)
    #pragma unroll
    for (int i = 0; i < 3; i++) {
      int oc = (wv*3 + i)*16 + lanelo;
      float bias = cb[oc];
      #pragma unroll
      for (int r = 0; r < 4; r++) {
        int tl = m*16 + ((lane >> 4) << 2) + r;
        int t = t0 + tl;
        float v = acc[m][i][r] + bias;
        float h0 = v / (1.f + fabsf(v));
        hbf[(size_t)(b*HROWS + t + PADR)*HID + oc] = f2bf(h0);
      }
    }
}

// ---------------- union-window layer body (templated on dil), 512 thr ------
// 8 waves = 2 M-groups(32 rows) x 4 N-groups. Twin M-group waves read the
// same B-frags ~in lockstep -> L1 absorbs the duplicate. 16 waves/CU.
template<int DIL>
__device__ __forceinline__
void layer_u_body(const unsigned short* __restrict__ hin,
                  unsigned short* __restrict__ hout,
                  const unsigned short* __restrict__ pk_dilh_l,
                  const float* __restrict__ dilh_b_l,
                  const float* __restrict__ Gl, const float* __restrict__ Cl,
                  const float* __restrict__ up_w,
                  unsigned short* flat)
{
  int b = blockIdx.y, t0 = blockIdx.x*64, tid = threadIdx.x;
  int wv = tid >> 6, lane = tid & 63, lanelo = lane & 15, lanehi = lane >> 4;
  int mwv = wv >> 2, nwv = wv & 3;

  const size_t hbase = (size_t)b * HROWS * HID;
  int rowbase0 = t0 - 5*DIL + PADR;            // >= 0 always
  const int W = 64 + 5*DIL;

  for (int c = tid; c < W*24; c += 512) {
    int row = c/24, cbk = c%24;
    uint4 v = *(const uint4*)&hin[hbase + (size_t)(rowbase0+row)*HID + cbk*8];
    *(uint4*)&flat[row*192 + ((cbk ^ (row&7))<<3)] = v;
  }
  __syncthreads();

  f32x4 accz[2][3], acct[2][3];
  f32x4 z4 = {0.f, 0.f, 0.f, 0.f};
  #pragma unroll
  for (int m = 0; m < 2; m++)
    #pragma unroll
    for (int i = 0; i < 3; i++) { accz[m][i] = z4; acct[m][i] = z4; }

  for (int tap = 0; tap < 6; tap++) {
    #pragma unroll
    for (int kc = 0; kc < 6; kc++) {
      bf16x8v A[2];
      #pragma unroll
      for (int m = 0; m < 2; m++) {
        int r = mwv*32 + m*16 + lanelo + tap*DIL;
        int cbk = kc*4 + lanehi;
        A[m] = *(const bf16x8v*)&flat[r*192 + ((cbk ^ (r&7))<<3)];
      }
      #pragma unroll
      for (int i = 0; i < 3; i++) {
        const unsigned short* bp =
            &pk_dilh_l[(size_t)(((tap*6 + kc)*24 + nwv*3 + i)*64 + lane)*8];
        bf16x8v Bz = *(const bf16x8v*)bp;
        bf16x8v Bt = *(const bf16x8v*)(bp + 12*512);
        #pragma unroll
        for (int m = 0; m < 2; m++) {
          accz[m][i] = mfma16(A[m], Bz, accz[m][i]);
          acct[m][i] = mfma16(A[m], Bt, acct[m][i]);
        }
      }
    }
  }

  float izc[3], itc[3], bzc[3], btc[3];
  #pragma unroll
  for (int i = 0; i < 3; i++) {
    int ocz = (nwv*3 + i)*16 + lanelo;
    izc[i] = Cl[ocz];       itc[i] = Cl[192 + ocz];
    bzc[i] = dilh_b_l[ocz]; btc[i] = dilh_b_l[192 + ocz];
  }
  #pragma unroll
  for (int m = 0; m < 2; m++) {
    #pragma unroll
    for (int r = 0; r < 4; r++) {
      int tl = mwv*32 + m*16 + (lanehi << 2) + r;
      int t = t0 + tl;
      int hr = tl + 5*DIL;
      int tp1 = t + 1;
      int q = tp1 / UPF; if (q > TAUX - 1) q = TAUX - 1;
      int ui = tp1 - q*UPF; if (ui > UPF - 1) ui = UPF - 1;
      float u = up_w[ui];
      const float* Gb = Gl + (size_t)(b*TAUX + q)*384;
      #pragma unroll
      for (int i = 0; i < 3; i++) {
        int ocz = (nwv*3 + i)*16 + lanelo;
        float iz = u*Gb[ocz]       + izc[i];
        float it = u*Gb[192 + ocz] + itc[i];
        float xz = (accz[m][i][r] + bzc[i]) * iz;
        float xt = (acct[m][i][r] + btc[i]) * it;
        float z  = 1.f / (1.f + __expf(-xz));
        float e2 = __expf(2.f*xt);
        float th = 1.f - 2.f/(e2 + 1.f);
        int cbh = ocz >> 3, jh = ocz & 7;
        unsigned short hob = flat[hr*192 + ((cbh ^ (hr&7))<<3) + jh];
        float hold = __uint_as_float(((unsigned int)hob) << 16);
        float hn = (1.f - z)*th + z*hold;
        hout[hbase + (size_t)(t + PADR)*HID + ocz] = f2bf(hn);
      }
    }
  }
}

// dil=1: LDS 26.5KB, (512,2) -> 16 waves/CU, VGPR cap 128 (no spill)
__global__ __launch_bounds__(512, 2)
void layer_u1_kernel(const unsigned short* __restrict__ hin,
                     unsigned short* __restrict__ hout,
                     const unsigned short* __restrict__ pk_dilh_l,
                     const float* __restrict__ dilh_b_l,
                     const float* __restrict__ Gl, const float* __restrict__ Cl,
                     const float* __restrict__ up_w)
{
  __shared__ __align__(16) unsigned short flat[69*192];
  layer_u_body<1>(hin, hout, pk_dilh_l, dilh_b_l, Gl, Cl, up_w, flat);
}

// dil=6: LDS 36.1KB, (512,2)
__global__ __launch_bounds__(512, 2)
void layer_u6_kernel(const unsigned short* __restrict__ hin,
                     unsigned short* __restrict__ hout,
                     const unsigned short* __restrict__ pk_dilh_l,
                     const float* __restrict__ dilh_b_l,
                     const float* __restrict__ Gl, const float* __restrict__ Cl,
                     const float* __restrict__ up_w)
{
  __shared__ __align__(16) unsigned short flat[94*192];
  layer_u_body<6>(hin, hout, pk_dilh_l, dilh_b_l, Gl, Cl, up_w, flat);
}

// ---------------- layer (dil 36): M=64, 512 thr, per-tap dbuf strips -------
__global__ __launch_bounds__(512, 2)
void layer_d_kernel(const unsigned short* __restrict__ hin,
                    unsigned short* __restrict__ hout,
                    const unsigned short* __restrict__ pk_dilh_l,
                    const float* __restrict__ dilh_b_l,
                    const float* __restrict__ Gl, const float* __restrict__ Cl,
                    const float* __restrict__ up_w)
{
  __shared__ __align__(16) unsigned short hs[2][64*192];   // 49152 B
  int b = blockIdx.y, t0 = blockIdx.x*64, tid = threadIdx.x;
  int wv = tid >> 6, lane = tid & 63, lanelo = lane & 15, lanehi = lane >> 4;
  int mwv = wv >> 2, nwv = wv & 3;

  const size_t hbase = (size_t)b * HROWS * HID;
  int rowbase0 = t0 - 180 + PADR;

  f32x4 accz[2][3], acct[2][3];
  f32x4 z4 = {0.f, 0.f, 0.f, 0.f};
  #pragma unroll
  for (int m = 0; m < 2; m++)
    #pragma unroll
    for (int i = 0; i < 3; i++) { accz[m][i] = z4; acct[m][i] = z4; }

  uint4 st[3];
  #pragma unroll
  for (int j = 0; j < 3; j++) {
    int c = tid + j*512, row = c/24, cbk = c%24;
    st[j] = *(const uint4*)&hin[hbase + (size_t)(rowbase0+row)*HID + cbk*8];
  }
  #pragma unroll
  for (int j = 0; j < 3; j++) {
    int c = tid + j*512, row = c/24, cbk = c%24;
    *(uint4*)&hs[0][row*192 + ((cbk ^ (row&7))<<3)] = st[j];
  }
  for (int tap = 0; tap < 6; tap++) {
    __syncthreads();
    if (tap < 5) {
      int rb = rowbase0 + (tap+1)*36;
      #pragma unroll
      for (int j = 0; j < 3; j++) {
        int c = tid + j*512, row = c/24, cbk = c%24;
        st[j] = *(const uint4*)&hin[hbase + (size_t)(rb+row)*HID + cbk*8];
      }
    }
    const unsigned short* bufc = hs[tap & 1];
    #pragma unroll
    for (int kc = 0; kc < 6; kc++) {
      bf16x8v A[2];
      #pragma unroll
      for (int m = 0; m < 2; m++) {
        int r = mwv*32 + m*16 + lanelo;
        int cbk = kc*4 + lanehi;
        A[m] = *(const bf16x8v*)&bufc[r*192 + ((cbk ^ (r&7))<<3)];
      }
      #pragma unroll
      for (int i = 0; i < 3; i++) {
        const unsigned short* bp =
            &pk_dilh_l[(size_t)(((tap*6 + kc)*24 + nwv*3 + i)*64 + lane)*8];
        bf16x8v Bz = *(const bf16x8v*)bp;
        bf16x8v Bt = *(const bf16x8v*)(bp + 12*512);
        #pragma unroll
        for (int m = 0; m < 2; m++) {
          accz[m][i] = mfma16(A[m], Bz, accz[m][i]);
          acct[m][i] = mfma16(A[m], Bt, acct[m][i]);
        }
      }
    }
    if (tap < 5) {
      unsigned short* bufn = hs[(tap+1) & 1];
      #pragma unroll
      for (int j = 0; j < 3; j++) {
        int c = tid + j*512, row = c/24, cbk = c%24;
        *(uint4*)&bufn[row*192 + ((cbk ^ (row&7))<<3)] = st[j];
      }
    }
  }

  float izc[3], itc[3], bzc[3], btc[3];
  #pragma unroll
  for (int i = 0; i < 3; i++) {
    int ocz = (nwv*3 + i)*16 + lanelo;
    izc[i] = Cl[ocz];       itc[i] = Cl[192 + ocz];
    bzc[i] = dilh_b_l[ocz]; btc[i] = dilh_b_l[192 + ocz];
  }
  #pragma unroll
  for (int m = 0; m < 2; m++) {
    #pragma unroll
    for (int r = 0; r < 4; r++) {
      int tl = mwv*32 + m*16 + (lanehi << 2) + r;
      int t = t0 + tl;
      int tp1 = t + 1;
      int q = tp1 / UPF; if (q > TAUX - 1) q = TAUX - 1;
      int ui = tp1 - q*UPF; if (ui > UPF - 1) ui = UPF - 1;
      float u = up_w[ui];
      const float* Gb = Gl + (size_t)(b*TAUX + q)*384;
      #pragma unroll
      for (int i = 0; i < 3; i++) {
        int ocz = (nwv*3 + i)*16 + lanelo;
        float iz = u*Gb[ocz]       + izc[i];
        float it = u*Gb[192 + ocz] + itc[i];
        float xz = (accz[m][i][r] + bzc[i]) * iz;
        float xt = (acct[m][i][r] + btc[i]) * it;
        float z  = 1.f / (1.f + __expf(-xz));
        float e2 = __expf(2.f*xt);
        float th = 1.f - 2.f/(e2 + 1.f);
        int cbh = ocz >> 3, jh = ocz & 7;
        unsigned short hob = hs[1][tl*192 + ((cbh ^ (tl&7))<<3) + jh];
        float hold = __uint_as_float(((unsigned int)hob) << 16);
        float hn = (1.f - z)*th + z*hold;
        hout[hbase + (size_t)(t + PADR)*HID + ocz] = f2bf(hn);
      }
    }
  }
}

// ---------------- fused tail, 512 thr: skipsum->relu->out1->relu->out2 -----
__global__ __launch_bounds__(512, 2)
void tail_kernel(const unsigned short* __restrict__ h_all,
                 const unsigned short* __restrict__ pk_skip,
                 const float* __restrict__ skip_b,
                 const unsigned short* __restrict__ pk1, const float* __restrict__ b1,
                 const unsigned short* __restrict__ pk2, const float* __restrict__ b2,
                 float* __restrict__ dout)
{
  __shared__ __align__(16) unsigned short ss[2][64*192];   // 49152 B
  int b = blockIdx.y, t0 = blockIdx.x*64, tid = threadIdx.x;
  int wv = tid >> 6, lane = tid & 63, lanelo = lane & 15, lanehi = lane >> 4;
  int mwv = wv >> 2, nwv = wv & 3;
  const size_t HS = (size_t)NB * HROWS * HID;
  f32x4 z4 = {0.f, 0.f, 0.f, 0.f};

  auto hsrc = [&](int l) {
    int slab = (l == 8) ? 0 : (l + 1);
    return h_all + (size_t)slab*HS + (size_t)b*HROWS*HID + (size_t)(t0 + PADR)*HID;
  };

  uint4 st[3];
  {
    const unsigned short* src = hsrc(0);
    #pragma unroll
    for (int j = 0; j < 3; j++) {
      int c = tid + j*512, row = c/24, cbk = c%24;
      st[j] = *(const uint4*)&src[(size_t)row*HID + cbk*8];
    }
    #pragma unroll
    for (int j = 0; j < 3; j++) {
      int c = tid + j*512, row = c/24, cbk = c%24;
      *(uint4*)&ss[0][row*192 + ((cbk ^ (row&7))<<3)] = st[j];
    }
  }

  f32x4 acc[2][4];
  #pragma unroll
  for (int m = 0; m < 2; m++)
    #pragma unroll
    for (int i = 0; i < 4; i++) acc[m][i] = z4;

  for (int l = 0; l < 9; l++) {
    __syncthreads();
    if (l < 8) {
      const unsigned short* src = hsrc(l + 1);
      #pragma unroll
      for (int j = 0; j < 3; j++) {
        int c = tid + j*512, row = c/24, cbk = c%24;
        st[j] = *(const uint4*)&src[(size_t)row*HID + cbk*8];
      }
    }
    const unsigned short* bufc = ss[l & 1];
    #pragma unroll
    for (int kc = 0; kc < 6; kc++) {
      bf16x8v A[2];
      #pragma unroll
      for (int m = 0; m < 2; m++) {
        int r = mwv*32 + m*16 + lanelo;
        int cbk = kc*4 + lanehi;
        A[m] = *(const bf16x8v*)&bufc[r*192 + ((cbk ^ (r&7))<<3)];
      }
      #pragma unroll
      for (int i = 0; i < 4; i++) {
        bf16x8v Bf = *(const bf16x8v*)
            &pk_skip[(size_t)(((l*6 + kc)*16 + nwv*4 + i)*64 + lane)*8];
        #pragma unroll
        for (int m = 0; m < 2; m++) acc[m][i] = mfma16(A[m], Bf, acc[m][i]);
      }
    }
    if (l < 8) {
      unsigned short* bufn = ss[(l+1) & 1];
      #pragma unroll
      for (int j = 0; j < 3; j++) {
        int c = tid + j*512, row = c/24, cbk = c%24;
        *(uint4*)&bufn[row*192 + ((cbk ^ (row&7))<<3)] = st[j];
      }
    }
  }
  __syncthreads();   // all skip A-reads done; reuse ss as [64][264] s-tile

  unsigned short* tile = &ss[0][0];
  #pragma unroll
  for (int i = 0; i < 4; i++) {
    int sc = (nwv*4 + i)*16 + lanelo;
    float bias = 0.f;
    #pragma unroll
    for (int l = 0; l < 9; l++) bias += skip_b[l*NSKIP + sc];
    #pragma unroll
    for (int m = 0; m < 2; m++) {
      #pragma unroll
      for (int r = 0; r < 4; r++) {
        int tl = mwv*32 + m*16 + (lanehi << 2) + r;
        tile[tl*264 + sc] = f2bf(fmaxf(acc[m][i][r] + bias, 0.f));
      }
    }
  }
  __syncthreads();

  // out1
  #pragma unroll
  for (int m = 0; m < 2; m++)
    #pragma unroll
    for (int i = 0; i < 4; i++) acc[m][i] = z4;
  for (int kc = 0; kc < 8; kc++) {
    bf16x8v A[2];
    int ko = kc*32 + (lanehi << 3);
    #pragma unroll
    for (int m = 0; m < 2; m++)
      A[m] = *(const bf16x8v*)&tile[(mwv*32 + m*16 + lanelo)*264 + ko];
    #pragma unroll
    for (int i = 0; i < 4; i++) {
      bf16x8v Bf = *(const bf16x8v*)&pk1[(size_t)((kc*16 + nwv*4 + i)*64 + lane)*8];
      #pragma unroll
      for (int m = 0; m < 2; m++) acc[m][i] = mfma16(A[m], Bf, acc[m][i]);
    }
  }
  __syncthreads();
  #pragma unroll
  for (int m = 0; m < 2; m++)
    #pragma unroll
    for (int i = 0; i < 4; i++) {
      int oq = (nwv*4 + i)*16 + lanelo;
      float bias = b1[oq];
      #pragma unroll
      for (int r = 0; r < 4; r++) {
        int tl = mwv*32 + m*16 + (lanehi << 2) + r;
        tile[tl*264 + oq] = f2bf(fmaxf(acc[m][i][r] + bias, 0.f));
      }
    }
  __syncthreads();

  // out2
  #pragma unroll
  for (int m = 0; m < 2; m++)
    #pragma unroll
    for (int i = 0; i < 4; i++) acc[m][i] = z4;
  for (int kc = 0; kc < 8; kc++) {
    bf16x8v A[2];
    int ko = kc*32 + (lanehi << 3);
    #pragma unroll
    for (int m = 0; m < 2; m++)
      A[m] = *(const bf16x8v*)&tile[(mwv*32 + m*16 + lanelo)*264 + ko];
    #pragma unroll
    for (int i = 0; i < 4; i++) {
      bf16x8v Bf = *(const bf16x8v*)&pk2[(size_t)((kc*16 + nwv*4 + i)*64 + lane)*8];
      #pragma unroll
      for (int m = 0; m < 2; m++) acc[m][i] = mfma16(A[m], Bf, acc[m][i]);
    }
  }
  // two fp32 half-tiles [32][260]; mwv==p waves own rows of half p
  float* so2 = (float*)&ss[0][0];
  #pragma unroll
  for (int p = 0; p < 2; p++) {
    __syncthreads();
    if (mwv == p) {
      #pragma unroll
      for (int m = 0; m < 2; m++) {
        #pragma unroll
        for (int i = 0; i < 4; i++) {
          int oq = (nwv*4 + i)*16 + lanelo;
          float bias = b2[oq];
          #pragma unroll
          for (int r = 0; r < 4; r++) {
            int lr = m*16 + (lanehi << 2) + r;
            so2[lr*260 + oq] = acc[m][i][r] + bias;
          }
        }
      }
    }
    __syncthreads();
    #pragma unroll
    for (int j = 0; j < 4; j++) {
      int c = tid + j*512, row = c >> 6, ch = c & 63;
      int t = t0 + p*32 + row;
      if (t < TLEN) {
        uint4 v = *(const uint4*)&so2[row*260 + ch*4];
        *(uint4*)&dout[(size_t)(b*TLEN + t)*NQ + ch*4] = v;
      }
    }
  }
}

// ---------------------------------------------------------------------------
extern "C" void kernel_launch(void* const* d_in, const int* in_sizes, int n_in,
                              void* d_out, int out_size, void* d_ws, size_t ws_size,
                              hipStream_t stream)
{
  const float* audio      = (const float*)d_in[0];
  const float* aux        = (const float*)d_in[1];
  const float* scale_in_w = (const float*)d_in[2];
  const float* scale_in_b = (const float*)d_in[3];
  const float* aux0_w     = (const float*)d_in[4];
  const float* aux0_b     = (const float*)d_in[5];
  const float* aux1_w     = (const float*)d_in[6];
  const float* aux1_b     = (const float*)d_in[7];
  const float* up_w       = (const float*)d_in[8];
  const float* up_b       = (const float*)d_in[9];
  const float* causal_w   = (const float*)d_in[10];
  const float* causal_b   = (const float*)d_in[11];
  const float* inx_w      = (const float*)d_in[12];
  const float* inx_b      = (const float*)d_in[13];
  const float* dilh_w     = (const float*)d_in[14];
  const float* dilh_b     = (const float*)d_in[15];
  const float* skip_w     = (const float*)d_in[16];
  const float* skip_b     = (const float*)d_in[17];
  const float* out1_w     = (const float*)d_in[18];
  const float* out1_b     = (const float*)d_in[19];
  const float* out2_w     = (const float*)d_in[20];
  const float* out2_b     = (const float*)d_in[21];

  char* ws = (char*)d_ws;
  size_t off = 0;
  auto alloc = [&](size_t bytes) -> void* {
    void* p = ws + off;
    off += (bytes + 255) & ~(size_t)255;
    return p;
  };
  unsigned short* pk_causal = (unsigned short*)alloc((size_t)6*8*12*64*8*2);
  unsigned short* pk_dilh   = (unsigned short*)alloc((size_t)9*6*6*24*64*8*2);
  unsigned short* pk_skip   = (unsigned short*)alloc((size_t)9*6*16*64*8*2);
  unsigned short* pk_out1   = (unsigned short*)alloc((size_t)8*16*64*8*2);
  unsigned short* pk_out2   = (unsigned short*)alloc((size_t)8*16*64*8*2);
  float* Cbuf    = (float*)alloc((size_t)9*384*4);
  float* a1      = (float*)alloc((size_t)NB*NAUX*TAUX*4);
  float* a2      = (float*)alloc((size_t)NB*162*TAUX*4);
  float* a3      = (float*)alloc((size_t)NB*486*TAUX*4);
  float* Gbuf    = (float*)alloc((size_t)9*NB*TAUX*384*4);
  const size_t HS = (size_t)NB*HROWS*HID;
  unsigned short* h_all = (unsigned short*)alloc((size_t)9*HS*2);  // slabs 0..8

  hipLaunchKernelGGL(prepack_kernel, dim3((9*6*6*24*64*8 + 255)/256), dim3(256), 0, stream,
                     causal_w, dilh_w, skip_w, out1_w, out2_w, inx_w, inx_b, up_b,
                     pk_causal, pk_dilh, pk_skip, pk_out1, pk_out2, Cbuf);
  hipLaunchKernelGGL(zpad_kernel, dim3((9*NB*PADR*HID + 255)/256), dim3(256), 0, stream,
                     h_all);
  hipLaunchKernelGGL(aux1_kernel, dim3(TAUX, NB), dim3(64), 0, stream,
                     aux, scale_in_w, scale_in_b, a1);
  hipLaunchKernelGGL(aux2_kernel, dim3(TAUX, NB), dim3(192), 0, stream,
                     a1, aux0_w, aux0_b, a2);
  hipLaunchKernelGGL(aux3_kernel, dim3(TAUX, NB), dim3(512), 0, stream,
                     a2, aux1_w, aux1_b, a3);
  hipLaunchKernelGGL(g_kernel, dim3(5, NB, 9), dim3(384), 0, stream,
                     a3, inx_w, Gbuf);
  hipLaunchKernelGGL(causal_kernel, dim3(NTILES, NB), dim3(256), 0, stream,
                     audio, pk_causal, causal_b, h_all /* slab 0 = h_0 */);

  const int dils[9] = {1, 6, 36, 1, 6, 36, 1, 6, 36};
  for (int l = 0; l < 9; l++) {
    const unsigned short* hin = h_all + (size_t)l*HS;
    unsigned short* hout      = (l == 8) ? h_all : h_all + (size_t)(l+1)*HS;
    const unsigned short* pkd = pk_dilh + (size_t)l*6*6*24*64*8;
    const float* dbl = dilh_b + (size_t)l*384;
    const float* Gl  = Gbuf + (size_t)l*NB*TAUX*384;
    const float* Cl  = Cbuf + (size_t)l*384;
    if (dils[l] == 1) {
      hipLaunchKernelGGL(layer_u1_kernel, dim3(NTILES, NB), dim3(512), 0, stream,
                         hin, hout, pkd, dbl, Gl, Cl, up_w);
    } else if (dils[l] == 6) {
      hipLaunchKernelGGL(layer_u6_kernel, dim3(NTILES, NB), dim3(512), 0, stream,
                         hin, hout, pkd, dbl, Gl, Cl, up_w);
    } else {
      hipLaunchKernelGGL(layer_d_kernel, dim3(NTILES, NB), dim3(512), 0, stream,
                         hin, hout, pkd, dbl, Gl, Cl, up_w);
    }
  }

  hipLaunchKernelGGL(tail_kernel, dim3(NTILES, NB), dim3(512), 0, stream,
                     h_all, pk_skip, skip_b, pk_out1, out1_b, pk_out2, out2_b,
                     (float*)d_out);
}